// Round 24
// baseline (2908.100 us; speedup 1.0000x reference)
//
#include <hip/hip_runtime.h>
#include <hip/hip_bf16.h>
#include <math.h>

// SimplifiedCTM on MI355X — round 24:
// - k_syn2/k_syn: K-chunked weight loads (2 x w[5] float4) + unified A/G rowsel
//   loop. r23: VGPR=180 capped waves at 2/SIMD despite 40KB LDS allowing 3-4
//   blocks/CU. Target VGPR<=140 -> 3 waves/SIMD, ~3x occupancy on the 40MB
//   L3 weight stream.
// - everything else identical to r23 (2.56 ms).

#define DEV __device__ __forceinline__
typedef const float* fp;
typedef const float4* f4p;

#define B_   16
#define P_   196
#define D_   512
#define H_   8
#define HD_  64
#define N_   2048
#define M_   25
#define SA_  512
#define SO_  1024
#define O_   1000
#define T_   16

DEV float sigmf(float x){ return 1.0f / (1.0f + expf(-x)); }
DEV float wred(float v) { for (int m = 32; m; m >>= 1) v += __shfl_xor(v, m); return v; }
DEV float f4dot(float4 a, float4 b) { return a.x*b.x + a.y*b.y + a.z*b.z + a.w*b.w; }

DEV float breduce_sum(float v, float* red) {
  int t = threadIdx.x;
  red[t] = v; __syncthreads();
  for (int s = 128; s > 0; s >>= 1) {
    if (t < s) red[t] += red[t + s];
    __syncthreads();
  }
  float r = red[0]; __syncthreads();
  return r;
}
DEV float breduce_max(float v, float* red) {
  int t = threadIdx.x;
  red[t] = v; __syncthreads();
  for (int s = 128; s > 0; s >>= 1) {
    if (t < s) red[t] = fmaxf(red[t], red[t + s]);
    __syncthreads();
  }
  float r = red[0]; __syncthreads();
  return r;
}

// ---- P1a: conv as tiled GEMM, Bs kk-major. grid (49, 8). ----
__global__ __launch_bounds__(256) void k_patch_tile(fp x, fp conv_w, fp conv_b, float* pt) {
  int i0 = blockIdx.x * 64;
  int j0 = blockIdx.y * 64;
  int tid = threadIdx.x;
  int ti = tid >> 4, tj = tid & 15;
  __shared__ float As[64][20];
  __shared__ float Bsx[16][68];
  float acc[4][4] = {{0,0,0,0},{0,0,0,0},{0,0,0,0},{0,0,0,0}};
  int p_loc = tid >> 2, k4 = (tid & 3) * 4;
  int bp = i0 + p_loc;
  int b = bp / P_, p = bp % P_;
  int ph = p / 14, pw = p % 14;
  const float* xbase = x + (size_t)b*3*224*224 + (size_t)(ph*16)*224 + pw*16;
  for (int kc = 0; kc < 48; kc++) {
    int ci = kc >> 4, qi = kc & 15;
    *(float4*)&As[p_loc][k4] = *(f4p)(xbase + ((size_t)ci*224 + qi)*224 + k4);
    float4 bv = *(f4p)(conv_w + (size_t)(j0 + p_loc)*768 + kc*16 + k4);
    Bsx[k4+0][p_loc] = bv.x; Bsx[k4+1][p_loc] = bv.y;
    Bsx[k4+2][p_loc] = bv.z; Bsx[k4+3][p_loc] = bv.w;
    __syncthreads();
    for (int kk = 0; kk < 16; kk++) {
      float a0 = As[ti*4+0][kk], a1 = As[ti*4+1][kk];
      float a2 = As[ti*4+2][kk], a3 = As[ti*4+3][kk];
      float4 bq = *(f4p)&Bsx[kk][tj*4];
      acc[0][0] += a0*bq.x; acc[0][1] += a0*bq.y; acc[0][2] += a0*bq.z; acc[0][3] += a0*bq.w;
      acc[1][0] += a1*bq.x; acc[1][1] += a1*bq.y; acc[1][2] += a1*bq.z; acc[1][3] += a1*bq.w;
      acc[2][0] += a2*bq.x; acc[2][1] += a2*bq.y; acc[2][2] += a2*bq.z; acc[2][3] += a2*bq.w;
      acc[3][0] += a3*bq.x; acc[3][1] += a3*bq.y; acc[3][2] += a3*bq.z; acc[3][3] += a3*bq.w;
    }
    __syncthreads();
  }
  for (int ii = 0; ii < 4; ii++)
    for (int jj = 0; jj < 4; jj++)
      pt[(size_t)(i0 + ti*4 + ii)*D_ + j0 + tj*4 + jj] = acc[ii][jj] + conv_b[j0 + tj*4 + jj];
}

// ---- P1b: LN + pos (in-place). grid 196. ----
__global__ __launch_bounds__(256) void k_pln(float* pt, fp g, fp bb, fp pos) {
  int bp0 = blockIdx.x * 16;
  int tid = threadIdx.x, wave = tid >> 6, lane = tid & 63;
  for (int i = 0; i < 4; i++) {
    int bp = bp0 + wave*4 + i;
    int p = bp % P_;
    float* row = pt + (size_t)bp*D_;
    float4 v0 = *(f4p)(row + lane*8);
    float4 v1 = *(f4p)(row + lane*8 + 4);
    float s = v0.x+v0.y+v0.z+v0.w + v1.x+v1.y+v1.z+v1.w;
    float q = f4dot(v0,v0) + f4dot(v1,v1);
    s = wred(s); q = wred(q);
    float mu = s / (float)D_;
    float var = q / (float)D_ - mu*mu;
    float rstd = 1.f / sqrtf(var + 1e-5f);
    for (int j = 0; j < 8; j++) {
      int c = lane*8 + j;
      float v = (j < 4) ? ((const float*)&v0)[j] : ((const float*)&v1)[j-4];
      row[c] = (v - mu)*rstd*g[c] + bb[c] + pos[p*D_ + c];
    }
  }
}

// ---- P2a: kv tiled GEMM, Bs kk-major. grid (49, 8). ----
__global__ __launch_bounds__(256) void k_kv_tile(const float* ptin, fp kv_w, fp kv_b, float* kvraw) {
  int i0 = blockIdx.x * 64;
  int j0 = blockIdx.y * 64;
  int tid = threadIdx.x;
  int ti = tid >> 4, tj = tid & 15;
  __shared__ float As[64][20];
  __shared__ float Bsx[16][68];
  float acc[4][4] = {{0,0,0,0},{0,0,0,0},{0,0,0,0},{0,0,0,0}};
  int p_loc = tid >> 2, k4 = (tid & 3) * 4;
  for (int kc = 0; kc < 32; kc++) {
    *(float4*)&As[p_loc][k4] = *(f4p)(ptin + (size_t)(i0 + p_loc)*D_ + kc*16 + k4);
    float4 bv = *(f4p)(kv_w + (size_t)(j0 + p_loc)*D_ + kc*16 + k4);
    Bsx[k4+0][p_loc] = bv.x; Bsx[k4+1][p_loc] = bv.y;
    Bsx[k4+2][p_loc] = bv.z; Bsx[k4+3][p_loc] = bv.w;
    __syncthreads();
    for (int kk = 0; kk < 16; kk++) {
      float a0 = As[ti*4+0][kk], a1 = As[ti*4+1][kk];
      float a2 = As[ti*4+2][kk], a3 = As[ti*4+3][kk];
      float4 bq = *(f4p)&Bsx[kk][tj*4];
      acc[0][0] += a0*bq.x; acc[0][1] += a0*bq.y; acc[0][2] += a0*bq.z; acc[0][3] += a0*bq.w;
      acc[1][0] += a1*bq.x; acc[1][1] += a1*bq.y; acc[1][2] += a1*bq.z; acc[1][3] += a1*bq.w;
      acc[2][0] += a2*bq.x; acc[2][1] += a2*bq.y; acc[2][2] += a2*bq.z; acc[2][3] += a2*bq.w;
      acc[3][0] += a3*bq.x; acc[3][1] += a3*bq.y; acc[3][2] += a3*bq.z; acc[3][3] += a3*bq.w;
    }
    __syncthreads();
  }
  for (int ii = 0; ii < 4; ii++)
    for (int jj = 0; jj < 4; jj++)
      kvraw[(size_t)(i0 + ti*4 + ii)*D_ + j0 + tj*4 + jj] = acc[ii][jj] + kv_b[j0 + tj*4 + jj];
}

// ---- P2b: LN in-place. grid 196. ----
__global__ __launch_bounds__(256) void k_kvln(float* kv, fp g, fp bb) {
  int bp0 = blockIdx.x * 16;
  int tid = threadIdx.x, wave = tid >> 6, lane = tid & 63;
  for (int i = 0; i < 4; i++) {
    int bp = bp0 + wave*4 + i;
    float* row = kv + (size_t)bp*D_;
    float4 v0 = *(f4p)(row + lane*8);
    float4 v1 = *(f4p)(row + lane*8 + 4);
    float s = v0.x+v0.y+v0.z+v0.w + v1.x+v1.y+v1.z+v1.w;
    float q = f4dot(v0,v0) + f4dot(v1,v1);
    s = wred(s); q = wred(q);
    float mu = s / (float)D_;
    float var = q / (float)D_ - mu*mu;
    float rstd = 1.f / sqrtf(var + 1e-5f);
    for (int j = 0; j < 8; j++) {
      int c = lane*8 + j;
      float v = (j < 4) ? ((const float*)&v0)[j] : ((const float*)&v1)[j-4];
      row[c] = (v - mu)*rstd*g[c] + bb[c];
    }
  }
}

// ---- P3: W_qc. grid (32,32). ----
__global__ __launch_bounds__(256) void k_wqc(fp aw, fp q_w, float* W_qc) {
  int i0 = blockIdx.x * 16, s0 = blockIdx.y * 16;
  int tid = threadIdx.x, il = tid >> 4, sl = tid & 15;
  __shared__ float s_wq[16][129];
  __shared__ float s_qw[128][17];
  float acc = 0.f;
  for (int kc = 0; kc < 4; kc++) {
    int k0 = kc * 128;
    for (int idx = tid; idx < 2048; idx += 256) {
      int r = idx >> 7, c = idx & 127;
      s_wq[r][c] = aw[(size_t)(i0 + r)*512 + k0 + c];
    }
    for (int idx = tid; idx < 2048; idx += 256) {
      int r = idx >> 4, c = idx & 15;
      s_qw[r][c] = q_w[(size_t)(k0 + r)*512 + s0 + c];
    }
    __syncthreads();
    for (int kk = 0; kk < 128; kk++)
      acc += s_wq[il][kk] * s_qw[kk][sl];
    __syncthreads();
  }
  W_qc[(size_t)(i0 + il)*512 + s0 + sl] = 0.125f * acc;
}

// ---- P3b: bc. grid 2. ----
__global__ __launch_bounds__(256) void k_wqcb(fp aw, fp q_b, fp ab, float* bc) {
  int i = blockIdx.x * 256 + threadIdx.x;
  float acc = ab[i];
  for (int j = 0; j < 512; j++) acc += aw[(size_t)i*512 + j] * q_b[j];
  bc[i] = 0.125f * acc;
}

// ---- P4: W_so = syn_w[:, :512] @ ow. grid (64, 8). ----
__global__ __launch_bounds__(256) void k_wso(fp syn_w, fp ow, float* W_so) {
  int i0 = blockIdx.x * 64;
  int j0 = blockIdx.y * 64;
  int tid = threadIdx.x;
  int ti = tid >> 4, tj = tid & 15;
  __shared__ float As[64][20];
  __shared__ float Bsx[16][68];
  float acc[4][4] = {{0,0,0,0},{0,0,0,0},{0,0,0,0},{0,0,0,0}};
  int p_loc = tid >> 2, k4 = (tid & 3) * 4;
  int kr = tid >> 4, c4 = (tid & 15) * 4;
  for (int kc = 0; kc < 32; kc++) {
    *(float4*)&As[p_loc][k4] = *(f4p)(syn_w + (size_t)(i0 + p_loc)*2560 + kc*16 + k4);
    *(float4*)&Bsx[kr][c4]   = *(f4p)(ow + (size_t)(kc*16 + kr)*512 + j0 + c4);
    __syncthreads();
    for (int kk = 0; kk < 16; kk++) {
      float a0 = As[ti*4+0][kk], a1 = As[ti*4+1][kk];
      float a2 = As[ti*4+2][kk], a3 = As[ti*4+3][kk];
      float4 bq = *(f4p)&Bsx[kk][tj*4];
      acc[0][0] += a0*bq.x; acc[0][1] += a0*bq.y; acc[0][2] += a0*bq.z; acc[0][3] += a0*bq.w;
      acc[1][0] += a1*bq.x; acc[1][1] += a1*bq.y; acc[1][2] += a1*bq.z; acc[1][3] += a1*bq.w;
      acc[2][0] += a2*bq.x; acc[2][1] += a2*bq.y; acc[2][2] += a2*bq.z; acc[2][3] += a2*bq.w;
      acc[3][0] += a3*bq.x; acc[3][1] += a3*bq.y; acc[3][2] += a3*bq.z; acc[3][3] += a3*bq.w;
    }
    __syncthreads();
  }
  for (int ii = 0; ii < 4; ii++)
    for (int jj = 0; jj < 4; jj++)
      W_so[(size_t)(i0 + ti*4 + ii)*512 + j0 + tj*4 + jj] = acc[ii][jj];
}

// ---- P4b: syn_b2. grid 16. ----
__global__ __launch_bounds__(256) void k_wsob(fp syn_w, fp syn_b, fp ob, float* syn_b2) {
  int r = blockIdx.x * 256 + threadIdx.x;
  float acc = syn_b[r];
  const float* wr = syn_w + (size_t)r*2560;
  for (int j = 0; j < 512; j++) acc += wr[j] * ob[j];
  syn_b2[r] = acc;
}

// ---- INIT ----
__global__ void k_init(fp start_state, fp start_trace, const int* oL, const int* oR,
                       fp decay_a, fp decay_o,
                       float* act, float* trace, float* aaA, float* baA,
                       float* aoA, float* boA, float* r_a, float* r_o) {
  int gid = blockIdx.x * 256 + threadIdx.x;
  if (gid < B_*N_*M_) {
    int bn = gid / M_, m = gid % M_;
    int n = bn % N_;
    trace[gid] = start_trace[n*M_ + m];
  }
  if (gid < B_*N_) act[gid] = start_state[gid & (N_-1)];
  if (gid < B_*SA_) { aaA[gid] = 0.f; baA[gid] = 0.f; }
  if (gid < B_*SO_) {
    int s = gid & (SO_-1);
    aoA[gid] = start_state[oL[s]] * start_state[oR[s]];
    boA[gid] = 1.0f;
  }
  if (gid < SA_) r_a[gid] = expf(-decay_a[gid]);
  if (gid < SO_) r_o[gid] = expf(-decay_o[gid]);
}

// ---- FAT: attn(t) [bid<128] + out(t-1) [bid>=128]. grid 228. ----
__global__ __launch_bounds__(256) void k_attout(
    const float* act,
    float* aaA, float* aaB, float* baA, float* baB,
    float* aoA, float* aoB, float* boA, float* boB,
    const float* r_a, const float* r_o,
    const float* W_qc, const float* bc, const float* kvb,
    fp aw, fp ab, fp out_w, fp out_b,
    const int* aL, const int* aR, const int* oL, const int* oR,
    float* av_ws, float* out, int t) {
  __shared__ float smem[8448];
  int bid = blockIdx.x;
  int tid = threadIdx.x, wave = tid >> 6, lane = tid & 63;

  if (bid < 128) {
    const float* aaR = (t & 1) ? aaB : aaA;  float* aaW = (t & 1) ? aaA : aaB;
    const float* baR = (t & 1) ? baB : baA;  float* baW = (t & 1) ? baA : baB;
    int b = bid >> 3, h = bid & 7;
    float* sact = smem;            // 512
    float* qhh  = smem + 512;      // 64
    float* qt   = smem + 576;      // 512
    float* mW   = smem + 1088;     // 4
    float* lW   = smem + 1092;     // 4
    float* zzL  = smem + 1600;     // 512
    float* zpart= smem + 2112;     // 2048
    for (int cc = 0; cc < 2; cc++) {
      int s = tid + cc*256;
      float r = r_a[s];
      float pair = act[b*N_ + aL[s]] * act[b*N_ + aR[s]];
      float a  = r*aaR[b*SA_ + s] + pair;
      float bt = r*baR[b*SA_ + s] + 1.0f;
      if (h == 0) { aaW[b*SA_ + s] = a; baW[b*SA_ + s] = bt; }
      sact[s] = a / sqrtf(bt);
    }
    __syncthreads();
    for (int k = 0; k < 16; k++) {
      int r = h*HD_ + wave*16 + k;
      const float* wr = W_qc + (size_t)r*512 + lane*4;
      float s = f4dot(*(f4p)(wr),       *(f4p)(&sact[lane*4]))
              + f4dot(*(f4p)(wr + 256), *(f4p)(&sact[lane*4 + 256]));
      s = wred(s);
      if (lane == 0) qhh[wave*16 + k] = s + bc[r];
    }
    __syncthreads();
    float acc0 = 0.f, acc1 = 0.f;
    for (int e = 0; e < HD_; e++) {
      float q = qhh[e];
      const float* ar = aw + (size_t)(512 + h*HD_ + e)*D_;
      acc0 += q * ar[tid];
      acc1 += q * ar[tid + 256];
    }
    qt[tid] = acc0; qt[tid + 256] = acc1;
    float kb = 0.f;
    for (int e = 0; e < HD_; e++) kb += qhh[e] * ab[512 + h*HD_ + e];
    __syncthreads();
    float qreg[8];
    for (int j = 0; j < 8; j++) qreg[j] = qt[lane*8 + j];
    float m = -1e30f, l = 0.f;
    float zz8[8] = {0,0,0,0,0,0,0,0};
    for (int p = wave*49; p < wave*49 + 49; p++) {
      const float* kvp = kvb + ((size_t)(b*P_ + p))*D_ + lane*8;
      float4 v0 = *(f4p)(kvp), v1 = *(f4p)(kvp + 4);
      float d = v0.x*qreg[0] + v0.y*qreg[1] + v0.z*qreg[2] + v0.w*qreg[3]
              + v1.x*qreg[4] + v1.y*qreg[5] + v1.z*qreg[6] + v1.w*qreg[7];
      d = wred(d);
      float s_p = d + kb;
      float m_new = fmaxf(m, s_p);
      float scale = expf(m - m_new);
      float e = expf(s_p - m_new);
      l = l*scale + e;
      zz8[0] = zz8[0]*scale + e*v0.x; zz8[1] = zz8[1]*scale + e*v0.y;
      zz8[2] = zz8[2]*scale + e*v0.z; zz8[3] = zz8[3]*scale + e*v0.w;
      zz8[4] = zz8[4]*scale + e*v1.x; zz8[5] = zz8[5]*scale + e*v1.y;
      zz8[6] = zz8[6]*scale + e*v1.z; zz8[7] = zz8[7]*scale + e*v1.w;
      m = m_new;
    }
    if (lane == 0) { mW[wave] = m; lW[wave] = l; }
    for (int j = 0; j < 8; j++) zpart[wave*512 + lane*8 + j] = zz8[j];
    __syncthreads();
    {
      float M0 = fmaxf(fmaxf(mW[0], mW[1]), fmaxf(mW[2], mW[3]));
      float f0 = expf(mW[0]-M0), f1 = expf(mW[1]-M0), f2 = expf(mW[2]-M0), f3 = expf(mW[3]-M0);
      float L = lW[0]*f0 + lW[1]*f1 + lW[2]*f2 + lW[3]*f3;
      float invL = 1.f / L;
      for (int cc = 0; cc < 2; cc++) {
        int c = tid + cc*256;
        zzL[c] = (zpart[c]*f0 + zpart[512 + c]*f1 + zpart[1024 + c]*f2 + zpart[1536 + c]*f3) * invL;
      }
    }
    __syncthreads();
    for (int k = 0; k < 16; k++) {
      int e2 = wave*16 + k;
      int r = 1024 + h*HD_ + e2;
      const float* wr = aw + (size_t)r*512 + lane*4;
      float s = f4dot(*(f4p)(wr),       *(f4p)(&zzL[lane*4]))
              + f4dot(*(f4p)(wr + 256), *(f4p)(&zzL[lane*4 + 256]));
      s = wred(s);
      if (lane == 0) av_ws[b*D_ + h*HD_ + e2] = s + ab[r];
    }
  } else if (t > 0) {
    int s_ = t - 1;
    const float* aoR = (s_ & 1) ? aoB : aoA;  float* aoW = (s_ & 1) ? aoA : aoB;
    const float* boR = (s_ & 1) ? boB : boA;  float* boW = (s_ & 1) ? boA : boB;
    int obid = bid - 128;
    int rb = obid >> 1, bg = obid & 1;
    float* s_sout = smem;          // 8*1024
    for (int i = 0; i < 32; i++) {
      int idx = tid + i*256;
      int bb = idx >> 10, s = idx & 1023;
      int b = bg*8 + bb;
      float r = r_o[s];
      float pair = act[b*N_ + oL[s]] * act[b*N_ + oR[s]];
      float a  = r*aoR[b*SO_ + s] + pair;
      float bt = r*boR[b*SO_ + s] + 1.f;
      if (rb == 0) { aoW[b*SO_ + s] = a; boW[b*SO_ + s] = bt; }
      s_sout[bb*1024 + s] = a / sqrtf(bt);
    }
    __syncthreads();
    for (int k = 0; k < 5; k++) {
      int r = rb*20 + wave*5 + k;
      const float* wr = out_w + (size_t)r*1024 + lane*4;
      float4 w0 = *(f4p)(wr),       w1 = *(f4p)(wr + 256),
             w2 = *(f4p)(wr + 512), w3 = *(f4p)(wr + 768);
      float pp[8];
      for (int bb = 0; bb < 8; bb++) {
        const float* pb = &s_sout[bb*1024 + lane*4];
        pp[bb] = f4dot(w0, *(f4p)(pb))       + f4dot(w1, *(f4p)(pb + 256))
               + f4dot(w2, *(f4p)(pb + 512)) + f4dot(w3, *(f4p)(pb + 768));
      }
      float obr = out_b[r];
      for (int bb = 0; bb < 8; bb++) {
        float s = wred(pp[bb]);
        if (lane == 0) out[((size_t)((bg*8 + bb)*O_ + r))*T_ + s_] = s + obr;
      }
    }
  }
}

// ---- T2c (fallback): attn_o = av @ ow.T + ob. grid (16,2). ----
__global__ __launch_bounds__(256) void k_ao2(const float* av_ws, fp ow, fp ob, float* attn_o) {
  int rb = blockIdx.x, bg = blockIdx.y;
  int tid = threadIdx.x, wave = tid >> 6, lane = tid & 63;
  __shared__ float s_a[8][516];
  for (int idx = tid; idx < 8*512; idx += 256) {
    int bb = idx >> 9, c = idx & 511;
    s_a[bb][c] = av_ws[(bg*8 + bb)*D_ + c];
  }
  __syncthreads();
  for (int k = 0; k < 8; k++) {
    int r = rb*32 + wave*8 + k;
    const float* wr = ow + (size_t)r*512 + lane*4;
    float4 w0 = *(f4p)(wr), w1 = *(f4p)(wr + 256);
    float pp[8];
    for (int bb = 0; bb < 8; bb++) {
      const float* pb = &s_a[bb][lane*4];
      pp[bb] = f4dot(w0, *(f4p)(pb)) + f4dot(w1, *(f4p)(pb + 256));
    }
    float obr = ob[r];
    for (int bb = 0; bb < 8; bb++) {
      float s = wred(pp[bb]);
      if (lane == 0) attn_o[(bg*8 + bb)*D_ + r] = s + obr;
    }
  }
}

// ---- T3 (big-ws): syn from [av, act] with W_so. grid (128,4).
//      K-chunked weight loads (w[5] x2) + unified A/G rowsel -> low VGPR. ----
__global__ __launch_bounds__(256) void k_syn2(const float* av_ws, const float* act,
                                              const float* W_so, fp syn_w, const float* syn_b2,
                                              float* ysyn, float* psum, float* psq) {
  int rb = blockIdx.x, bg = blockIdx.y;      // bg in [0,4)
  int tid = threadIdx.x, wave = tid >> 6, lane = tid & 63;
  __shared__ float pre4[4*2560];   // 40,960 B
  for (int bb = 0; bb < 4; bb++) {
    int b = bg*4 + bb;
    for (int i = tid; i < 2560; i += 256)
      pre4[bb*2560 + i] = (i < 512) ? av_ws[b*D_ + i] : act[b*N_ + (i - 512)];
  }
  __syncthreads();
  float lsum[4] = {0,0,0,0}, lsq[4] = {0,0,0,0};
  for (int k = 0; k < 4; k++) {
    int pr = rb*16 + wave*4 + k;
    float sA[4], sG[4];
    for (int rowsel = 0; rowsel < 2; rowsel++) {
      int r = pr + rowsel*2048;
      float pp[4] = {0,0,0,0};
      for (int j0 = 0; j0 < 10; j0 += 5) {
        float4 w[5];
        for (int j = 0; j < 5; j++) {
          int jj = j0 + j;
          w[j] = (jj < 2) ? *(f4p)(W_so + (size_t)r*512 + jj*256 + lane*4)
                          : *(f4p)(syn_w + (size_t)r*2560 + 512 + (jj-2)*256 + lane*4);
        }
        for (int j = 0; j < 5; j++) {
          int idx = lane*4 + (j0+j)*256;
          for (int bb = 0; bb < 4; bb++)
            pp[bb] += f4dot(w[j], *(f4p)(&pre4[bb*2560 + idx]));
        }
      }
      float sb = syn_b2[r];
      if (rowsel == 0) { for (int bb = 0; bb < 4; bb++) sA[bb] = wred(pp[bb]) + sb; }
      else             { for (int bb = 0; bb < 4; bb++) sG[bb] = wred(pp[bb]) + sb; }
    }
    for (int bb = 0; bb < 4; bb++) {
      float v = sA[bb] * sigmf(sG[bb]);
      lsum[bb] += v; lsq[bb] += v*v;
      if (lane == 0) ysyn[(size_t)(bg*4 + bb)*N_ + pr] = v;
    }
  }
  __syncthreads();
  if (lane == 0)
    for (int bb = 0; bb < 4; bb++) {
      pre4[wave*4 + bb]      = lsum[bb];
      pre4[16 + wave*4 + bb] = lsq[bb];
    }
  __syncthreads();
  if (tid < 4) {
    float s1 = pre4[tid] + pre4[4 + tid] + pre4[8 + tid] + pre4[12 + tid];
    float s2 = pre4[16 + tid] + pre4[20 + tid] + pre4[24 + tid] + pre4[28 + tid];
    psum[rb*16 + bg*4 + tid] = s1;
    psq [rb*16 + bg*4 + tid] = s2;
  }
}

// ---- T3 (fallback): syn from [attn_o, act]. grid (128,4). K-chunked. ----
__global__ __launch_bounds__(256) void k_syn(const float* attn_o, const float* act,
                                             fp syn_w, fp syn_b, float* ysyn,
                                             float* psum, float* psq) {
  int rb = blockIdx.x, bg = blockIdx.y;      // bg in [0,4)
  int tid = threadIdx.x, wave = tid >> 6, lane = tid & 63;
  __shared__ float pre4[4*2560];
  for (int bb = 0; bb < 4; bb++) {
    int b = bg*4 + bb;
    for (int i = tid; i < 2560; i += 256)
      pre4[bb*2560 + i] = (i < 512) ? attn_o[b*D_ + i] : act[b*N_ + (i - 512)];
  }
  __syncthreads();
  float lsum[4] = {0,0,0,0}, lsq[4] = {0,0,0,0};
  for (int k = 0; k < 4; k++) {
    int pr = rb*16 + wave*4 + k;
    float sA[4], sG[4];
    for (int rowsel = 0; rowsel < 2; rowsel++) {
      int r = pr + rowsel*2048;
      float pp[4] = {0,0,0,0};
      for (int j0 = 0; j0 < 10; j0 += 5) {
        float4 w[5];
        for (int j = 0; j < 5; j++)
          w[j] = *(f4p)(syn_w + (size_t)r*2560 + (j0+j)*256 + lane*4);
        for (int j = 0; j < 5; j++) {
          int idx = lane*4 + (j0+j)*256;
          for (int bb = 0; bb < 4; bb++)
            pp[bb] += f4dot(w[j], *(f4p)(&pre4[bb*2560 + idx]));
        }
      }
      float sb = syn_b[r];
      if (rowsel == 0) { for (int bb = 0; bb < 4; bb++) sA[bb] = wred(pp[bb]) + sb; }
      else             { for (int bb = 0; bb < 4; bb++) sG[bb] = wred(pp[bb]) + sb; }
    }
    for (int bb = 0; bb < 4; bb++) {
      float v = sA[bb] * sigmf(sG[bb]);
      lsum[bb] += v; lsq[bb] += v*v;
      if (lane == 0) ysyn[(size_t)(bg*4 + bb)*N_ + pr] = v;
    }
  }
  __syncthreads();
  if (lane == 0)
    for (int bb = 0; bb < 4; bb++) {
      pre4[wave*4 + bb]      = lsum[bb];
      pre4[16 + wave*4 + bb] = lsq[bb];
    }
  __syncthreads();
  if (tid < 4) {
    float s1 = pre4[tid] + pre4[4 + tid] + pre4[8 + tid] + pre4[12 + tid];
    float s2 = pre4[16 + tid] + pre4[20 + tid] + pre4[24 + tid] + pre4[28 + tid];
    psum[rb*16 + bg*4 + tid] = s1;
    psq [rb*16 + bg*4 + tid] = s2;
  }
}

// ---- T5: NLM; LN from 128 partials + trace shift fused; fc2 on 256 thr. grid 2048. ----
__global__ __launch_bounds__(256) void k_nlm(float* trace, const float* ysyn,
                                             const float* psum, const float* psq,
                                             fp sg, fp sb2,
                                             fp fc1_w, fp fc1_b, fp fc2_w, fp fc2_b,
                                             fp nlmT, float* act) {
  int n = blockIdx.x, tid = threadIdx.x;
  __shared__ float tr[B_][M_];
  __shared__ float uu[256][17];
  __shared__ float h1[128][17];
  __shared__ float vout[B_][2];
  __shared__ float s_mu[16], s_rstd[16];
  {
    int b = tid >> 4, j = tid & 15;
    float s1 = 0.f, s2 = 0.f;
    for (int rb = j; rb < 128; rb += 16) { s1 += psum[rb*16 + b]; s2 += psq[rb*16 + b]; }
    for (int m = 8; m; m >>= 1) { s1 += __shfl_xor(s1, m); s2 += __shfl_xor(s2, m); }
    if (j == 0) {
      float mu = s1 / (float)N_;
      s_mu[b] = mu;
      s_rstd[b] = 1.f / sqrtf(s2 / (float)N_ - mu*mu + 1e-5f);
    }
  }
  __syncthreads();
  for (int i = tid; i < B_*M_; i += 256) {
    int b = i / M_, m = i % M_;
    float v;
    if (m < M_-1) v = trace[((size_t)(b*N_ + n))*M_ + m + 1];
    else          v = (ysyn[(size_t)b*N_ + n] - s_mu[b]) * s_rstd[b] * sg[n] + sb2[n];
    tr[b][m] = v;
  }
  __syncthreads();
  for (int i = tid; i < B_*M_; i += 256) {
    int b = i / M_, m = i % M_;
    trace[((size_t)(b*N_ + n))*M_ + m] = tr[b][m];
  }
  float w25[M_];
  for (int m = 0; m < M_; m++) w25[m] = fc1_w[((size_t)n*M_ + m)*256 + tid];
  float bias = fc1_b[n*256 + tid];
  for (int b = 0; b < B_; b++) {
    float u = bias;
    for (int m = 0; m < M_; m++) u += tr[b][m]*w25[m];
    uu[tid][b] = u;
  }
  __syncthreads();
  if (tid < 128) {
    for (int b = 0; b < B_; b++)
      h1[tid][b] = uu[tid][b] * sigmf(uu[tid + 128][b]);
  }
  __syncthreads();
  {
    int b = tid >> 4, o = (tid >> 3) & 1, part = tid & 7;
    const float* f2 = fc2_w + (size_t)n*256;
    float acc = 0.f;
    for (int i = 0; i < 16; i++) {
      int hh = part*16 + i;
      acc += h1[hh][b] * f2[hh*2 + o];
    }
    for (int m2 = 4; m2; m2 >>= 1) acc += __shfl_xor(acc, m2);
    if (part == 0) vout[b][o] = acc + fc2_b[n*2 + o];
  }
  __syncthreads();
  if (tid < B_) {
    act[tid*N_ + n] = vout[tid][0] * sigmf(vout[tid][1]) / nlmT[0];
  }
}

// ---- standalone OUT (last tick). grid (50,2). ----
__global__ __launch_bounds__(256) void k_out(const float* act, const float* aoR, const float* boR,
                                             float* aoW, float* boW, const float* r_o,
                                             const int* L, const int* R,
                                             fp out_w, fp out_b, float* out, int t) {
  int rb = blockIdx.x, bg = blockIdx.y;
  int tid = threadIdx.x, wave = tid >> 6, lane = tid & 63;
  __shared__ float s_sout[8][1024];
  for (int i = 0; i < 32; i++) {
    int idx = tid + i*256;
    int bb = idx >> 10, s = idx & 1023;
    int b = bg*8 + bb;
    float r = r_o[s];
    float pair = act[b*N_ + L[s]] * act[b*N_ + R[s]];
    float a  = r*aoR[b*SO_ + s] + pair;
    float bt = r*boR[b*SO_ + s] + 1.f;
    if (rb == 0) { aoW[b*SO_ + s] = a; boW[b*SO_ + s] = bt; }
    s_sout[bb][s] = a / sqrtf(bt);
  }
  __syncthreads();
  for (int k = 0; k < 5; k++) {
    int r = rb*20 + wave*5 + k;
    const float* wr = out_w + (size_t)r*1024 + lane*4;
    float4 w0 = *(f4p)(wr),       w1 = *(f4p)(wr + 256),
           w2 = *(f4p)(wr + 512), w3 = *(f4p)(wr + 768);
    float pp[8];
    for (int bb = 0; bb < 8; bb++) {
      const float* pb = &s_sout[bb][lane*4];
      pp[bb] = f4dot(w0, *(f4p)(pb))       + f4dot(w1, *(f4p)(pb + 256))
             + f4dot(w2, *(f4p)(pb + 512)) + f4dot(w3, *(f4p)(pb + 768));
    }
    float obr = out_b[r];
    for (int bb = 0; bb < 8; bb++) {
      float s = wred(pp[bb]);
      if (lane == 0) out[((size_t)((bg*8 + bb)*O_ + r))*T_ + t] = s + obr;
    }
  }
}

// ---- T7: entropy. grid (16,16). ----
__global__ __launch_bounds__(256) void k_final(float* out) {
  int b = blockIdx.x, t = blockIdx.y, tid = threadIdx.x;
  __shared__ float red[256];
  float lm = -1e30f;
  for (int o = tid; o < O_; o += 256) lm = fmaxf(lm, out[((size_t)(b*O_ + o))*T_ + t]);
  float Mx = breduce_max(lm, red);
  float le = 0.f;
  for (int o = tid; o < O_; o += 256) le += expf(out[((size_t)(b*O_ + o))*T_ + t] - Mx);
  float S = breduce_sum(le, red);
  float lt = 0.f;
  for (int o = tid; o < O_; o += 256) {
    float pr = expf(out[((size_t)(b*O_ + o))*T_ + t] - Mx) / S;
    lt += pr * logf(pr + 1e-10f);
  }
  float E = breduce_sum(lt, red);
  if (tid == 0)
    out[(size_t)B_*O_*T_ + b*T_ + t] = -E / logf((float)O_);
}

extern "C" void kernel_launch(void* const* d_in, const int* in_sizes, int n_in,
                              void* d_out, int out_size, void* d_ws, size_t ws_size,
                              hipStream_t stream) {
  (void)in_sizes; (void)n_in; (void)out_size;
  fp x          = (fp)d_in[0];
  fp conv_w     = (fp)d_in[1];
  fp conv_b     = (fp)d_in[2];
  fp patch_ln_g = (fp)d_in[3];
  fp patch_ln_b = (fp)d_in[4];
  fp pos        = (fp)d_in[5];
  fp kv_w       = (fp)d_in[6];
  fp kv_b       = (fp)d_in[7];
  fp kv_ln_g    = (fp)d_in[8];
  fp kv_ln_b    = (fp)d_in[9];
  fp q_w        = (fp)d_in[10];
  fp q_b        = (fp)d_in[11];
  fp attn_in_w  = (fp)d_in[12];
  fp attn_in_b  = (fp)d_in[13];
  fp attn_out_w = (fp)d_in[14];
  fp attn_out_b = (fp)d_in[15];
  fp syn_w      = (fp)d_in[16];
  fp syn_b      = (fp)d_in[17];
  fp syn_ln_g   = (fp)d_in[18];
  fp syn_ln_b   = (fp)d_in[19];
  fp fc1_w      = (fp)d_in[20];
  fp fc1_b      = (fp)d_in[21];
  fp fc2_w      = (fp)d_in[22];
  fp fc2_b      = (fp)d_in[23];
  fp nlm_T      = (fp)d_in[24];
  fp start_state= (fp)d_in[25];
  fp start_trace= (fp)d_in[26];
  fp decay_a    = (fp)d_in[27];
  fp decay_o    = (fp)d_in[28];
  fp out_w      = (fp)d_in[29];
  fp out_b      = (fp)d_in[30];
  const int* act_left  = (const int*)d_in[31];
  const int* act_right = (const int*)d_in[32];
  const int* out_left  = (const int*)d_in[33];
  const int* out_right = (const int*)d_in[34];

  float* ws = (float*)d_ws;
  float* pt     = ws;                          // precompute only
  float* act    = ws + 0;                      // 32768
  float* trace  = ws + 32768;                  // 819200 -> 851968
  float* aaA    = ws + 851968;                 // 8192
  float* aaB    = ws + 860160;                 // 8192
  float* baA    = ws + 868352;                 // 8192
  float* baB    = ws + 876544;                 // 8192 -> 884736
  float* aoA    = ws + 884736;                 // 16384
  float* aoB    = ws + 901120;                 // 16384
  float* boA    = ws + 917504;                 // 16384
  float* boB    = ws + 933888;                 // 16384 -> 950272
  float* attn_o = ws + 958464;                 // 8192 (fallback only)
  float* ysyn   = ws + 966656;                 // 32768 -> 999424
  float* psum   = ws + 999424;                 // 2048
  float* psq    = ws + 1001472;                // 2048 -> 1003520
  float* av_ws  = ws + 1064960;                // 8192
  float* r_a    = ws + 1073152;                // 512
  float* r_o    = ws + 1073664;                // 1024 -> 1074688
  float* W_qc   = ws + 1074688;                // 262144 -> 1336832
  float* bc     = ws + 1336832;                // 512 -> 1337344 < 1605632
  float* kvb    = ws + 1605632;                // 1605632 -> 3211264
  float* W_so   = ws + 3211264;                // 2097152 -> 5308416
  float* syn_b2 = ws + 5308416;                // 4096 -> 5312512
  const bool big = ws_size >= (size_t)5312512 * 4;

  k_patch_tile<<<dim3(49, 8), dim3(256), 0, stream>>>(x, conv_w, conv_b, pt);
  k_pln<<<dim3(196), dim3(256), 0, stream>>>(pt, patch_ln_g, patch_ln_b, pos);
  k_kv_tile<<<dim3(49, 8), dim3(256), 0, stream>>>(pt, kv_w, kv_b, kvb);
  k_kvln<<<dim3(196), dim3(256), 0, stream>>>(kvb, kv_ln_g, kv_ln_b);
  k_wqc<<<dim3(32, 32), dim3(256), 0, stream>>>(attn_in_w, q_w, W_qc);
  k_wqcb<<<dim3(2), dim3(256), 0, stream>>>(attn_in_w, q_b, attn_in_b, bc);
  if (big) {
    k_wso<<<dim3(64, 8), dim3(256), 0, stream>>>(syn_w, attn_out_w, W_so);
    k_wsob<<<dim3(16), dim3(256), 0, stream>>>(syn_w, syn_b, attn_out_b, syn_b2);
  }
  k_init<<<dim3((B_*N_*M_ + 255)/256), dim3(256), 0, stream>>>(start_state, start_trace,
        out_left, out_right, decay_a, decay_o, act, trace, aaA, baA, aoA, boA, r_a, r_o);

  for (int t = 0; t < T_; t++) {
    k_attout<<<dim3(228), dim3(256), 0, stream>>>(
        act, aaA, aaB, baA, baB, aoA, aoB, boA, boB, r_a, r_o,
        W_qc, bc, kvb, attn_in_w, attn_in_b, out_w, out_b,
        act_left, act_right, out_left, out_right, av_ws, (float*)d_out, t);
    if (big) {
      k_syn2<<<dim3(128, 4), dim3(256), 0, stream>>>(av_ws, act, W_so, syn_w, syn_b2,
                                                     ysyn, psum, psq);
    } else {
      k_ao2<<<dim3(16, 2), dim3(256), 0, stream>>>(av_ws, attn_out_w, attn_out_b, attn_o);
      k_syn<<<dim3(128, 4), dim3(256), 0, stream>>>(attn_o, act, syn_w, syn_b, ysyn, psum, psq);
    }
    k_nlm<<<dim3(N_), dim3(256), 0, stream>>>(trace, ysyn, psum, psq, syn_ln_g, syn_ln_b,
                                              fc1_w, fc1_b, fc2_w, fc2_b, nlm_T, act);
  }
  {
    int t = T_ - 1;
    const float* aoR = (t & 1) ? aoB : aoA;  float* aoW = (t & 1) ? aoA : aoB;
    const float* boR = (t & 1) ? boB : boA;  float* boW = (t & 1) ? boA : boB;
    k_out<<<dim3(50, 2), dim3(256), 0, stream>>>(act, aoR, boR, aoW, boW, r_o,
                                                 out_left, out_right, out_w, out_b,
                                                 (float*)d_out, t);
  }
  k_final<<<dim3(16, 16), dim3(256), 0, stream>>>((float*)d_out);
}

// Round 25
// 2555.742 us; speedup vs baseline: 1.1379x; 1.1379x over previous
//
#include <hip/hip_runtime.h>
#include <hip/hip_bf16.h>
#include <math.h>

// SimplifiedCTM on MI355X — round 25: restore r23 exactly (2.558 ms best-known).
// r24's K-chunked/rowsel-unified syn spilled (VGPR 256, WRITE 26MB scratch):
// conditional weight-pointer select inside the hot loop defeats regalloc.
// Straight-line two-block weight loads (VGPR 180, 64us) restored.

#define DEV __device__ __forceinline__
typedef const float* fp;
typedef const float4* f4p;

#define B_   16
#define P_   196
#define D_   512
#define H_   8
#define HD_  64
#define N_   2048
#define M_   25
#define SA_  512
#define SO_  1024
#define O_   1000
#define T_   16

DEV float sigmf(float x){ return 1.0f / (1.0f + expf(-x)); }
DEV float wred(float v) { for (int m = 32; m; m >>= 1) v += __shfl_xor(v, m); return v; }
DEV float f4dot(float4 a, float4 b) { return a.x*b.x + a.y*b.y + a.z*b.z + a.w*b.w; }

DEV float breduce_sum(float v, float* red) {
  int t = threadIdx.x;
  red[t] = v; __syncthreads();
  for (int s = 128; s > 0; s >>= 1) {
    if (t < s) red[t] += red[t + s];
    __syncthreads();
  }
  float r = red[0]; __syncthreads();
  return r;
}
DEV float breduce_max(float v, float* red) {
  int t = threadIdx.x;
  red[t] = v; __syncthreads();
  for (int s = 128; s > 0; s >>= 1) {
    if (t < s) red[t] = fmaxf(red[t], red[t + s]);
    __syncthreads();
  }
  float r = red[0]; __syncthreads();
  return r;
}

// ---- P1a: conv as tiled GEMM, Bs kk-major. grid (49, 8). ----
__global__ __launch_bounds__(256) void k_patch_tile(fp x, fp conv_w, fp conv_b, float* pt) {
  int i0 = blockIdx.x * 64;
  int j0 = blockIdx.y * 64;
  int tid = threadIdx.x;
  int ti = tid >> 4, tj = tid & 15;
  __shared__ float As[64][20];
  __shared__ float Bsx[16][68];
  float acc[4][4] = {{0,0,0,0},{0,0,0,0},{0,0,0,0},{0,0,0,0}};
  int p_loc = tid >> 2, k4 = (tid & 3) * 4;
  int bp = i0 + p_loc;
  int b = bp / P_, p = bp % P_;
  int ph = p / 14, pw = p % 14;
  const float* xbase = x + (size_t)b*3*224*224 + (size_t)(ph*16)*224 + pw*16;
  for (int kc = 0; kc < 48; kc++) {
    int ci = kc >> 4, qi = kc & 15;
    *(float4*)&As[p_loc][k4] = *(f4p)(xbase + ((size_t)ci*224 + qi)*224 + k4);
    float4 bv = *(f4p)(conv_w + (size_t)(j0 + p_loc)*768 + kc*16 + k4);
    Bsx[k4+0][p_loc] = bv.x; Bsx[k4+1][p_loc] = bv.y;
    Bsx[k4+2][p_loc] = bv.z; Bsx[k4+3][p_loc] = bv.w;
    __syncthreads();
    for (int kk = 0; kk < 16; kk++) {
      float a0 = As[ti*4+0][kk], a1 = As[ti*4+1][kk];
      float a2 = As[ti*4+2][kk], a3 = As[ti*4+3][kk];
      float4 bq = *(f4p)&Bsx[kk][tj*4];
      acc[0][0] += a0*bq.x; acc[0][1] += a0*bq.y; acc[0][2] += a0*bq.z; acc[0][3] += a0*bq.w;
      acc[1][0] += a1*bq.x; acc[1][1] += a1*bq.y; acc[1][2] += a1*bq.z; acc[1][3] += a1*bq.w;
      acc[2][0] += a2*bq.x; acc[2][1] += a2*bq.y; acc[2][2] += a2*bq.z; acc[2][3] += a2*bq.w;
      acc[3][0] += a3*bq.x; acc[3][1] += a3*bq.y; acc[3][2] += a3*bq.z; acc[3][3] += a3*bq.w;
    }
    __syncthreads();
  }
  for (int ii = 0; ii < 4; ii++)
    for (int jj = 0; jj < 4; jj++)
      pt[(size_t)(i0 + ti*4 + ii)*D_ + j0 + tj*4 + jj] = acc[ii][jj] + conv_b[j0 + tj*4 + jj];
}

// ---- P1b: LN + pos (in-place). grid 196. ----
__global__ __launch_bounds__(256) void k_pln(float* pt, fp g, fp bb, fp pos) {
  int bp0 = blockIdx.x * 16;
  int tid = threadIdx.x, wave = tid >> 6, lane = tid & 63;
  for (int i = 0; i < 4; i++) {
    int bp = bp0 + wave*4 + i;
    int p = bp % P_;
    float* row = pt + (size_t)bp*D_;
    float4 v0 = *(f4p)(row + lane*8);
    float4 v1 = *(f4p)(row + lane*8 + 4);
    float s = v0.x+v0.y+v0.z+v0.w + v1.x+v1.y+v1.z+v1.w;
    float q = f4dot(v0,v0) + f4dot(v1,v1);
    s = wred(s); q = wred(q);
    float mu = s / (float)D_;
    float var = q / (float)D_ - mu*mu;
    float rstd = 1.f / sqrtf(var + 1e-5f);
    for (int j = 0; j < 8; j++) {
      int c = lane*8 + j;
      float v = (j < 4) ? ((const float*)&v0)[j] : ((const float*)&v1)[j-4];
      row[c] = (v - mu)*rstd*g[c] + bb[c] + pos[p*D_ + c];
    }
  }
}

// ---- P2a: kv tiled GEMM, Bs kk-major. grid (49, 8). ----
__global__ __launch_bounds__(256) void k_kv_tile(const float* ptin, fp kv_w, fp kv_b, float* kvraw) {
  int i0 = blockIdx.x * 64;
  int j0 = blockIdx.y * 64;
  int tid = threadIdx.x;
  int ti = tid >> 4, tj = tid & 15;
  __shared__ float As[64][20];
  __shared__ float Bsx[16][68];
  float acc[4][4] = {{0,0,0,0},{0,0,0,0},{0,0,0,0},{0,0,0,0}};
  int p_loc = tid >> 2, k4 = (tid & 3) * 4;
  for (int kc = 0; kc < 32; kc++) {
    *(float4*)&As[p_loc][k4] = *(f4p)(ptin + (size_t)(i0 + p_loc)*D_ + kc*16 + k4);
    float4 bv = *(f4p)(kv_w + (size_t)(j0 + p_loc)*D_ + kc*16 + k4);
    Bsx[k4+0][p_loc] = bv.x; Bsx[k4+1][p_loc] = bv.y;
    Bsx[k4+2][p_loc] = bv.z; Bsx[k4+3][p_loc] = bv.w;
    __syncthreads();
    for (int kk = 0; kk < 16; kk++) {
      float a0 = As[ti*4+0][kk], a1 = As[ti*4+1][kk];
      float a2 = As[ti*4+2][kk], a3 = As[ti*4+3][kk];
      float4 bq = *(f4p)&Bsx[kk][tj*4];
      acc[0][0] += a0*bq.x; acc[0][1] += a0*bq.y; acc[0][2] += a0*bq.z; acc[0][3] += a0*bq.w;
      acc[1][0] += a1*bq.x; acc[1][1] += a1*bq.y; acc[1][2] += a1*bq.z; acc[1][3] += a1*bq.w;
      acc[2][0] += a2*bq.x; acc[2][1] += a2*bq.y; acc[2][2] += a2*bq.z; acc[2][3] += a2*bq.w;
      acc[3][0] += a3*bq.x; acc[3][1] += a3*bq.y; acc[3][2] += a3*bq.z; acc[3][3] += a3*bq.w;
    }
    __syncthreads();
  }
  for (int ii = 0; ii < 4; ii++)
    for (int jj = 0; jj < 4; jj++)
      kvraw[(size_t)(i0 + ti*4 + ii)*D_ + j0 + tj*4 + jj] = acc[ii][jj] + kv_b[j0 + tj*4 + jj];
}

// ---- P2b: LN in-place. grid 196. ----
__global__ __launch_bounds__(256) void k_kvln(float* kv, fp g, fp bb) {
  int bp0 = blockIdx.x * 16;
  int tid = threadIdx.x, wave = tid >> 6, lane = tid & 63;
  for (int i = 0; i < 4; i++) {
    int bp = bp0 + wave*4 + i;
    float* row = kv + (size_t)bp*D_;
    float4 v0 = *(f4p)(row + lane*8);
    float4 v1 = *(f4p)(row + lane*8 + 4);
    float s = v0.x+v0.y+v0.z+v0.w + v1.x+v1.y+v1.z+v1.w;
    float q = f4dot(v0,v0) + f4dot(v1,v1);
    s = wred(s); q = wred(q);
    float mu = s / (float)D_;
    float var = q / (float)D_ - mu*mu;
    float rstd = 1.f / sqrtf(var + 1e-5f);
    for (int j = 0; j < 8; j++) {
      int c = lane*8 + j;
      float v = (j < 4) ? ((const float*)&v0)[j] : ((const float*)&v1)[j-4];
      row[c] = (v - mu)*rstd*g[c] + bb[c];
    }
  }
}

// ---- P3: W_qc. grid (32,32). ----
__global__ __launch_bounds__(256) void k_wqc(fp aw, fp q_w, float* W_qc) {
  int i0 = blockIdx.x * 16, s0 = blockIdx.y * 16;
  int tid = threadIdx.x, il = tid >> 4, sl = tid & 15;
  __shared__ float s_wq[16][129];
  __shared__ float s_qw[128][17];
  float acc = 0.f;
  for (int kc = 0; kc < 4; kc++) {
    int k0 = kc * 128;
    for (int idx = tid; idx < 2048; idx += 256) {
      int r = idx >> 7, c = idx & 127;
      s_wq[r][c] = aw[(size_t)(i0 + r)*512 + k0 + c];
    }
    for (int idx = tid; idx < 2048; idx += 256) {
      int r = idx >> 4, c = idx & 15;
      s_qw[r][c] = q_w[(size_t)(k0 + r)*512 + s0 + c];
    }
    __syncthreads();
    for (int kk = 0; kk < 128; kk++)
      acc += s_wq[il][kk] * s_qw[kk][sl];
    __syncthreads();
  }
  W_qc[(size_t)(i0 + il)*512 + s0 + sl] = 0.125f * acc;
}

// ---- P3b: bc. grid 2. ----
__global__ __launch_bounds__(256) void k_wqcb(fp aw, fp q_b, fp ab, float* bc) {
  int i = blockIdx.x * 256 + threadIdx.x;
  float acc = ab[i];
  for (int j = 0; j < 512; j++) acc += aw[(size_t)i*512 + j] * q_b[j];
  bc[i] = 0.125f * acc;
}

// ---- P4: W_so = syn_w[:, :512] @ ow. grid (64, 8). ----
__global__ __launch_bounds__(256) void k_wso(fp syn_w, fp ow, float* W_so) {
  int i0 = blockIdx.x * 64;
  int j0 = blockIdx.y * 64;
  int tid = threadIdx.x;
  int ti = tid >> 4, tj = tid & 15;
  __shared__ float As[64][20];
  __shared__ float Bsx[16][68];
  float acc[4][4] = {{0,0,0,0},{0,0,0,0},{0,0,0,0},{0,0,0,0}};
  int p_loc = tid >> 2, k4 = (tid & 3) * 4;
  int kr = tid >> 4, c4 = (tid & 15) * 4;
  for (int kc = 0; kc < 32; kc++) {
    *(float4*)&As[p_loc][k4] = *(f4p)(syn_w + (size_t)(i0 + p_loc)*2560 + kc*16 + k4);
    *(float4*)&Bsx[kr][c4]   = *(f4p)(ow + (size_t)(kc*16 + kr)*512 + j0 + c4);
    __syncthreads();
    for (int kk = 0; kk < 16; kk++) {
      float a0 = As[ti*4+0][kk], a1 = As[ti*4+1][kk];
      float a2 = As[ti*4+2][kk], a3 = As[ti*4+3][kk];
      float4 bq = *(f4p)&Bsx[kk][tj*4];
      acc[0][0] += a0*bq.x; acc[0][1] += a0*bq.y; acc[0][2] += a0*bq.z; acc[0][3] += a0*bq.w;
      acc[1][0] += a1*bq.x; acc[1][1] += a1*bq.y; acc[1][2] += a1*bq.z; acc[1][3] += a1*bq.w;
      acc[2][0] += a2*bq.x; acc[2][1] += a2*bq.y; acc[2][2] += a2*bq.z; acc[2][3] += a2*bq.w;
      acc[3][0] += a3*bq.x; acc[3][1] += a3*bq.y; acc[3][2] += a3*bq.z; acc[3][3] += a3*bq.w;
    }
    __syncthreads();
  }
  for (int ii = 0; ii < 4; ii++)
    for (int jj = 0; jj < 4; jj++)
      W_so[(size_t)(i0 + ti*4 + ii)*512 + j0 + tj*4 + jj] = acc[ii][jj];
}

// ---- P4b: syn_b2. grid 16. ----
__global__ __launch_bounds__(256) void k_wsob(fp syn_w, fp syn_b, fp ob, float* syn_b2) {
  int r = blockIdx.x * 256 + threadIdx.x;
  float acc = syn_b[r];
  const float* wr = syn_w + (size_t)r*2560;
  for (int j = 0; j < 512; j++) acc += wr[j] * ob[j];
  syn_b2[r] = acc;
}

// ---- INIT ----
__global__ void k_init(fp start_state, fp start_trace, const int* oL, const int* oR,
                       fp decay_a, fp decay_o,
                       float* act, float* trace, float* aaA, float* baA,
                       float* aoA, float* boA, float* r_a, float* r_o) {
  int gid = blockIdx.x * 256 + threadIdx.x;
  if (gid < B_*N_*M_) {
    int bn = gid / M_, m = gid % M_;
    int n = bn % N_;
    trace[gid] = start_trace[n*M_ + m];
  }
  if (gid < B_*N_) act[gid] = start_state[gid & (N_-1)];
  if (gid < B_*SA_) { aaA[gid] = 0.f; baA[gid] = 0.f; }
  if (gid < B_*SO_) {
    int s = gid & (SO_-1);
    aoA[gid] = start_state[oL[s]] * start_state[oR[s]];
    boA[gid] = 1.0f;
  }
  if (gid < SA_) r_a[gid] = expf(-decay_a[gid]);
  if (gid < SO_) r_o[gid] = expf(-decay_o[gid]);
}

// ---- FAT: attn(t) [bid<128] + out(t-1) [bid>=128]. grid 228. ----
__global__ __launch_bounds__(256) void k_attout(
    const float* act,
    float* aaA, float* aaB, float* baA, float* baB,
    float* aoA, float* aoB, float* boA, float* boB,
    const float* r_a, const float* r_o,
    const float* W_qc, const float* bc, const float* kvb,
    fp aw, fp ab, fp out_w, fp out_b,
    const int* aL, const int* aR, const int* oL, const int* oR,
    float* av_ws, float* out, int t) {
  __shared__ float smem[8448];
  int bid = blockIdx.x;
  int tid = threadIdx.x, wave = tid >> 6, lane = tid & 63;

  if (bid < 128) {
    const float* aaR = (t & 1) ? aaB : aaA;  float* aaW = (t & 1) ? aaA : aaB;
    const float* baR = (t & 1) ? baB : baA;  float* baW = (t & 1) ? baA : baB;
    int b = bid >> 3, h = bid & 7;
    float* sact = smem;            // 512
    float* qhh  = smem + 512;      // 64
    float* qt   = smem + 576;      // 512
    float* mW   = smem + 1088;     // 4
    float* lW   = smem + 1092;     // 4
    float* zzL  = smem + 1600;     // 512
    float* zpart= smem + 2112;     // 2048
    for (int cc = 0; cc < 2; cc++) {
      int s = tid + cc*256;
      float r = r_a[s];
      float pair = act[b*N_ + aL[s]] * act[b*N_ + aR[s]];
      float a  = r*aaR[b*SA_ + s] + pair;
      float bt = r*baR[b*SA_ + s] + 1.0f;
      if (h == 0) { aaW[b*SA_ + s] = a; baW[b*SA_ + s] = bt; }
      sact[s] = a / sqrtf(bt);
    }
    __syncthreads();
    for (int k = 0; k < 16; k++) {
      int r = h*HD_ + wave*16 + k;
      const float* wr = W_qc + (size_t)r*512 + lane*4;
      float s = f4dot(*(f4p)(wr),       *(f4p)(&sact[lane*4]))
              + f4dot(*(f4p)(wr + 256), *(f4p)(&sact[lane*4 + 256]));
      s = wred(s);
      if (lane == 0) qhh[wave*16 + k] = s + bc[r];
    }
    __syncthreads();
    float acc0 = 0.f, acc1 = 0.f;
    for (int e = 0; e < HD_; e++) {
      float q = qhh[e];
      const float* ar = aw + (size_t)(512 + h*HD_ + e)*D_;
      acc0 += q * ar[tid];
      acc1 += q * ar[tid + 256];
    }
    qt[tid] = acc0; qt[tid + 256] = acc1;
    float kb = 0.f;
    for (int e = 0; e < HD_; e++) kb += qhh[e] * ab[512 + h*HD_ + e];
    __syncthreads();
    float qreg[8];
    for (int j = 0; j < 8; j++) qreg[j] = qt[lane*8 + j];
    float m = -1e30f, l = 0.f;
    float zz8[8] = {0,0,0,0,0,0,0,0};
    for (int p = wave*49; p < wave*49 + 49; p++) {
      const float* kvp = kvb + ((size_t)(b*P_ + p))*D_ + lane*8;
      float4 v0 = *(f4p)(kvp), v1 = *(f4p)(kvp + 4);
      float d = v0.x*qreg[0] + v0.y*qreg[1] + v0.z*qreg[2] + v0.w*qreg[3]
              + v1.x*qreg[4] + v1.y*qreg[5] + v1.z*qreg[6] + v1.w*qreg[7];
      d = wred(d);
      float s_p = d + kb;
      float m_new = fmaxf(m, s_p);
      float scale = expf(m - m_new);
      float e = expf(s_p - m_new);
      l = l*scale + e;
      zz8[0] = zz8[0]*scale + e*v0.x; zz8[1] = zz8[1]*scale + e*v0.y;
      zz8[2] = zz8[2]*scale + e*v0.z; zz8[3] = zz8[3]*scale + e*v0.w;
      zz8[4] = zz8[4]*scale + e*v1.x; zz8[5] = zz8[5]*scale + e*v1.y;
      zz8[6] = zz8[6]*scale + e*v1.z; zz8[7] = zz8[7]*scale + e*v1.w;
      m = m_new;
    }
    if (lane == 0) { mW[wave] = m; lW[wave] = l; }
    for (int j = 0; j < 8; j++) zpart[wave*512 + lane*8 + j] = zz8[j];
    __syncthreads();
    {
      float M0 = fmaxf(fmaxf(mW[0], mW[1]), fmaxf(mW[2], mW[3]));
      float f0 = expf(mW[0]-M0), f1 = expf(mW[1]-M0), f2 = expf(mW[2]-M0), f3 = expf(mW[3]-M0);
      float L = lW[0]*f0 + lW[1]*f1 + lW[2]*f2 + lW[3]*f3;
      float invL = 1.f / L;
      for (int cc = 0; cc < 2; cc++) {
        int c = tid + cc*256;
        zzL[c] = (zpart[c]*f0 + zpart[512 + c]*f1 + zpart[1024 + c]*f2 + zpart[1536 + c]*f3) * invL;
      }
    }
    __syncthreads();
    for (int k = 0; k < 16; k++) {
      int e2 = wave*16 + k;
      int r = 1024 + h*HD_ + e2;
      const float* wr = aw + (size_t)r*512 + lane*4;
      float s = f4dot(*(f4p)(wr),       *(f4p)(&zzL[lane*4]))
              + f4dot(*(f4p)(wr + 256), *(f4p)(&zzL[lane*4 + 256]));
      s = wred(s);
      if (lane == 0) av_ws[b*D_ + h*HD_ + e2] = s + ab[r];
    }
  } else if (t > 0) {
    int s_ = t - 1;
    const float* aoR = (s_ & 1) ? aoB : aoA;  float* aoW = (s_ & 1) ? aoA : aoB;
    const float* boR = (s_ & 1) ? boB : boA;  float* boW = (s_ & 1) ? boA : boB;
    int obid = bid - 128;
    int rb = obid >> 1, bg = obid & 1;
    float* s_sout = smem;          // 8*1024
    for (int i = 0; i < 32; i++) {
      int idx = tid + i*256;
      int bb = idx >> 10, s = idx & 1023;
      int b = bg*8 + bb;
      float r = r_o[s];
      float pair = act[b*N_ + oL[s]] * act[b*N_ + oR[s]];
      float a  = r*aoR[b*SO_ + s] + pair;
      float bt = r*boR[b*SO_ + s] + 1.f;
      if (rb == 0) { aoW[b*SO_ + s] = a; boW[b*SO_ + s] = bt; }
      s_sout[bb*1024 + s] = a / sqrtf(bt);
    }
    __syncthreads();
    for (int k = 0; k < 5; k++) {
      int r = rb*20 + wave*5 + k;
      const float* wr = out_w + (size_t)r*1024 + lane*4;
      float4 w0 = *(f4p)(wr),       w1 = *(f4p)(wr + 256),
             w2 = *(f4p)(wr + 512), w3 = *(f4p)(wr + 768);
      float pp[8];
      for (int bb = 0; bb < 8; bb++) {
        const float* pb = &s_sout[bb*1024 + lane*4];
        pp[bb] = f4dot(w0, *(f4p)(pb))       + f4dot(w1, *(f4p)(pb + 256))
               + f4dot(w2, *(f4p)(pb + 512)) + f4dot(w3, *(f4p)(pb + 768));
      }
      float obr = out_b[r];
      for (int bb = 0; bb < 8; bb++) {
        float s = wred(pp[bb]);
        if (lane == 0) out[((size_t)((bg*8 + bb)*O_ + r))*T_ + s_] = s + obr;
      }
    }
  }
}

// ---- T2c (fallback): attn_o = av @ ow.T + ob. grid (16,2). ----
__global__ __launch_bounds__(256) void k_ao2(const float* av_ws, fp ow, fp ob, float* attn_o) {
  int rb = blockIdx.x, bg = blockIdx.y;
  int tid = threadIdx.x, wave = tid >> 6, lane = tid & 63;
  __shared__ float s_a[8][516];
  for (int idx = tid; idx < 8*512; idx += 256) {
    int bb = idx >> 9, c = idx & 511;
    s_a[bb][c] = av_ws[(bg*8 + bb)*D_ + c];
  }
  __syncthreads();
  for (int k = 0; k < 8; k++) {
    int r = rb*32 + wave*8 + k;
    const float* wr = ow + (size_t)r*512 + lane*4;
    float4 w0 = *(f4p)(wr), w1 = *(f4p)(wr + 256);
    float pp[8];
    for (int bb = 0; bb < 8; bb++) {
      const float* pb = &s_a[bb][lane*4];
      pp[bb] = f4dot(w0, *(f4p)(pb)) + f4dot(w1, *(f4p)(pb + 256));
    }
    float obr = ob[r];
    for (int bb = 0; bb < 8; bb++) {
      float s = wred(pp[bb]);
      if (lane == 0) attn_o[(bg*8 + bb)*D_ + r] = s + obr;
    }
  }
}

// ---- T3 (big-ws): syn from [av, act] with W_so. grid (128,4): 4 batches/block,
//      LDS 40,960B -> 3-4 blocks/CU. psum[128][16] preserved. ----
__global__ __launch_bounds__(256) void k_syn2(const float* av_ws, const float* act,
                                              const float* W_so, fp syn_w, const float* syn_b2,
                                              float* ysyn, float* psum, float* psq) {
  int rb = blockIdx.x, bg = blockIdx.y;      // bg in [0,4)
  int tid = threadIdx.x, wave = tid >> 6, lane = tid & 63;
  __shared__ float pre4[4*2560];   // 40,960 B
  for (int bb = 0; bb < 4; bb++) {
    int b = bg*4 + bb;
    for (int i = tid; i < 2560; i += 256)
      pre4[bb*2560 + i] = (i < 512) ? av_ws[b*D_ + i] : act[b*N_ + (i - 512)];
  }
  __syncthreads();
  float lsum[4] = {0,0,0,0}, lsq[4] = {0,0,0,0};
  for (int k = 0; k < 4; k++) {
    int pr = rb*16 + wave*4 + k;
    float sA[4];
    {
      float4 wreg[10];
      wreg[0] = *(f4p)(W_so + (size_t)pr*512 + lane*4);
      wreg[1] = *(f4p)(W_so + (size_t)pr*512 + 256 + lane*4);
      for (int j = 2; j < 10; j++)
        wreg[j] = *(f4p)(syn_w + (size_t)pr*2560 + 512 + (j-2)*256 + lane*4);
      float pp[4] = {0,0,0,0};
      for (int j = 0; j < 10; j++) {
        int idx = lane*4 + j*256;
        for (int bb = 0; bb < 4; bb++)
          pp[bb] += f4dot(wreg[j], *(f4p)(&pre4[bb*2560 + idx]));
      }
      float sb = syn_b2[pr];
      for (int bb = 0; bb < 4; bb++) sA[bb] = wred(pp[bb]) + sb;
    }
    {
      int r2 = pr + 2048;
      float4 wreg[10];
      wreg[0] = *(f4p)(W_so + (size_t)r2*512 + lane*4);
      wreg[1] = *(f4p)(W_so + (size_t)r2*512 + 256 + lane*4);
      for (int j = 2; j < 10; j++)
        wreg[j] = *(f4p)(syn_w + (size_t)r2*2560 + 512 + (j-2)*256 + lane*4);
      float pp[4] = {0,0,0,0};
      for (int j = 0; j < 10; j++) {
        int idx = lane*4 + j*256;
        for (int bb = 0; bb < 4; bb++)
          pp[bb] += f4dot(wreg[j], *(f4p)(&pre4[bb*2560 + idx]));
      }
      float sb = syn_b2[r2];
      for (int bb = 0; bb < 4; bb++) {
        float sG = wred(pp[bb]) + sb;
        float v = sA[bb] * sigmf(sG);
        lsum[bb] += v; lsq[bb] += v*v;
        if (lane == 0) ysyn[(size_t)(bg*4 + bb)*N_ + pr] = v;
      }
    }
  }
  // reduce 4 waves' partials via pre4 reuse
  __syncthreads();
  if (lane == 0)
    for (int bb = 0; bb < 4; bb++) {
      pre4[wave*4 + bb]      = lsum[bb];
      pre4[16 + wave*4 + bb] = lsq[bb];
    }
  __syncthreads();
  if (tid < 4) {
    float s1 = pre4[tid] + pre4[4 + tid] + pre4[8 + tid] + pre4[12 + tid];
    float s2 = pre4[16 + tid] + pre4[20 + tid] + pre4[24 + tid] + pre4[28 + tid];
    psum[rb*16 + bg*4 + tid] = s1;
    psq [rb*16 + bg*4 + tid] = s2;
  }
}

// ---- T3 (fallback): syn from [attn_o, act]. grid (128,4). ----
__global__ __launch_bounds__(256) void k_syn(const float* attn_o, const float* act,
                                             fp syn_w, fp syn_b, float* ysyn,
                                             float* psum, float* psq) {
  int rb = blockIdx.x, bg = blockIdx.y;      // bg in [0,4)
  int tid = threadIdx.x, wave = tid >> 6, lane = tid & 63;
  __shared__ float pre4[4*2560];
  for (int bb = 0; bb < 4; bb++) {
    int b = bg*4 + bb;
    for (int i = tid; i < 2560; i += 256)
      pre4[bb*2560 + i] = (i < 512) ? attn_o[b*D_ + i] : act[b*N_ + (i - 512)];
  }
  __syncthreads();
  float lsum[4] = {0,0,0,0}, lsq[4] = {0,0,0,0};
  for (int k = 0; k < 4; k++) {
    int pr = rb*16 + wave*4 + k;
    float sA[4];
    {
      const float* wr = syn_w + (size_t)pr*2560 + lane*4;
      float4 wreg[10];
      for (int j = 0; j < 10; j++) wreg[j] = *(f4p)(wr + j*256);
      float pp[4] = {0,0,0,0};
      for (int j = 0; j < 10; j++) {
        int idx = lane*4 + j*256;
        for (int bb = 0; bb < 4; bb++)
          pp[bb] += f4dot(wreg[j], *(f4p)(&pre4[bb*2560 + idx]));
      }
      float sb = syn_b[pr];
      for (int bb = 0; bb < 4; bb++) sA[bb] = wred(pp[bb]) + sb;
    }
    {
      int r2 = pr + 2048;
      const float* wr = syn_w + (size_t)r2*2560 + lane*4;
      float4 wreg[10];
      for (int j = 0; j < 10; j++) wreg[j] = *(f4p)(wr + j*256);
      float pp[4] = {0,0,0,0};
      for (int j = 0; j < 10; j++) {
        int idx = lane*4 + j*256;
        for (int bb = 0; bb < 4; bb++)
          pp[bb] += f4dot(wreg[j], *(f4p)(&pre4[bb*2560 + idx]));
      }
      float sb = syn_b[r2];
      for (int bb = 0; bb < 4; bb++) {
        float sG = wred(pp[bb]) + sb;
        float v = sA[bb] * sigmf(sG);
        lsum[bb] += v; lsq[bb] += v*v;
        if (lane == 0) ysyn[(size_t)(bg*4 + bb)*N_ + pr] = v;
      }
    }
  }
  __syncthreads();
  if (lane == 0)
    for (int bb = 0; bb < 4; bb++) {
      pre4[wave*4 + bb]      = lsum[bb];
      pre4[16 + wave*4 + bb] = lsq[bb];
    }
  __syncthreads();
  if (tid < 4) {
    float s1 = pre4[tid] + pre4[4 + tid] + pre4[8 + tid] + pre4[12 + tid];
    float s2 = pre4[16 + tid] + pre4[20 + tid] + pre4[24 + tid] + pre4[28 + tid];
    psum[rb*16 + bg*4 + tid] = s1;
    psq [rb*16 + bg*4 + tid] = s2;
  }
}

// ---- T5: NLM; LN from 128 partials + trace shift fused; fc2 on 256 thr. grid 2048. ----
__global__ __launch_bounds__(256) void k_nlm(float* trace, const float* ysyn,
                                             const float* psum, const float* psq,
                                             fp sg, fp sb2,
                                             fp fc1_w, fp fc1_b, fp fc2_w, fp fc2_b,
                                             fp nlmT, float* act) {
  int n = blockIdx.x, tid = threadIdx.x;
  __shared__ float tr[B_][M_];
  __shared__ float uu[256][17];
  __shared__ float h1[128][17];
  __shared__ float vout[B_][2];
  __shared__ float s_mu[16], s_rstd[16];
  {
    int b = tid >> 4, j = tid & 15;
    float s1 = 0.f, s2 = 0.f;
    for (int rb = j; rb < 128; rb += 16) { s1 += psum[rb*16 + b]; s2 += psq[rb*16 + b]; }
    for (int m = 8; m; m >>= 1) { s1 += __shfl_xor(s1, m); s2 += __shfl_xor(s2, m); }
    if (j == 0) {
      float mu = s1 / (float)N_;
      s_mu[b] = mu;
      s_rstd[b] = 1.f / sqrtf(s2 / (float)N_ - mu*mu + 1e-5f);
    }
  }
  __syncthreads();
  for (int i = tid; i < B_*M_; i += 256) {
    int b = i / M_, m = i % M_;
    float v;
    if (m < M_-1) v = trace[((size_t)(b*N_ + n))*M_ + m + 1];
    else          v = (ysyn[(size_t)b*N_ + n] - s_mu[b]) * s_rstd[b] * sg[n] + sb2[n];
    tr[b][m] = v;
  }
  __syncthreads();
  for (int i = tid; i < B_*M_; i += 256) {
    int b = i / M_, m = i % M_;
    trace[((size_t)(b*N_ + n))*M_ + m] = tr[b][m];
  }
  float w25[M_];
  for (int m = 0; m < M_; m++) w25[m] = fc1_w[((size_t)n*M_ + m)*256 + tid];
  float bias = fc1_b[n*256 + tid];
  for (int b = 0; b < B_; b++) {
    float u = bias;
    for (int m = 0; m < M_; m++) u += tr[b][m]*w25[m];
    uu[tid][b] = u;
  }
  __syncthreads();
  if (tid < 128) {
    for (int b = 0; b < B_; b++)
      h1[tid][b] = uu[tid][b] * sigmf(uu[tid + 128][b]);
  }
  __syncthreads();
  {
    int b = tid >> 4, o = (tid >> 3) & 1, part = tid & 7;
    const float* f2 = fc2_w + (size_t)n*256;
    float acc = 0.f;
    for (int i = 0; i < 16; i++) {
      int hh = part*16 + i;
      acc += h1[hh][b] * f2[hh*2 + o];
    }
    for (int m2 = 4; m2; m2 >>= 1) acc += __shfl_xor(acc, m2);
    if (part == 0) vout[b][o] = acc + fc2_b[n*2 + o];
  }
  __syncthreads();
  if (tid < B_) {
    act[tid*N_ + n] = vout[tid][0] * sigmf(vout[tid][1]) / nlmT[0];
  }
}

// ---- standalone OUT (last tick). grid (50,2). ----
__global__ __launch_bounds__(256) void k_out(const float* act, const float* aoR, const float* boR,
                                             float* aoW, float* boW, const float* r_o,
                                             const int* L, const int* R,
                                             fp out_w, fp out_b, float* out, int t) {
  int rb = blockIdx.x, bg = blockIdx.y;
  int tid = threadIdx.x, wave = tid >> 6, lane = tid & 63;
  __shared__ float s_sout[8][1024];
  for (int i = 0; i < 32; i++) {
    int idx = tid + i*256;
    int bb = idx >> 10, s = idx & 1023;
    int b = bg*8 + bb;
    float r = r_o[s];
    float pair = act[b*N_ + L[s]] * act[b*N_ + R[s]];
    float a  = r*aoR[b*SO_ + s] + pair;
    float bt = r*boR[b*SO_ + s] + 1.f;
    if (rb == 0) { aoW[b*SO_ + s] = a; boW[b*SO_ + s] = bt; }
    s_sout[bb][s] = a / sqrtf(bt);
  }
  __syncthreads();
  for (int k = 0; k < 5; k++) {
    int r = rb*20 + wave*5 + k;
    const float* wr = out_w + (size_t)r*1024 + lane*4;
    float4 w0 = *(f4p)(wr),       w1 = *(f4p)(wr + 256),
           w2 = *(f4p)(wr + 512), w3 = *(f4p)(wr + 768);
    float pp[8];
    for (int bb = 0; bb < 8; bb++) {
      const float* pb = &s_sout[bb][lane*4];
      pp[bb] = f4dot(w0, *(f4p)(pb))       + f4dot(w1, *(f4p)(pb + 256))
             + f4dot(w2, *(f4p)(pb + 512)) + f4dot(w3, *(f4p)(pb + 768));
    }
    float obr = out_b[r];
    for (int bb = 0; bb < 8; bb++) {
      float s = wred(pp[bb]);
      if (lane == 0) out[((size_t)((bg*8 + bb)*O_ + r))*T_ + t] = s + obr;
    }
  }
}

// ---- T7: entropy. grid (16,16). ----
__global__ __launch_bounds__(256) void k_final(float* out) {
  int b = blockIdx.x, t = blockIdx.y, tid = threadIdx.x;
  __shared__ float red[256];
  float lm = -1e30f;
  for (int o = tid; o < O_; o += 256) lm = fmaxf(lm, out[((size_t)(b*O_ + o))*T_ + t]);
  float Mx = breduce_max(lm, red);
  float le = 0.f;
  for (int o = tid; o < O_; o += 256) le += expf(out[((size_t)(b*O_ + o))*T_ + t] - Mx);
  float S = breduce_sum(le, red);
  float lt = 0.f;
  for (int o = tid; o < O_; o += 256) {
    float pr = expf(out[((size_t)(b*O_ + o))*T_ + t] - Mx) / S;
    lt += pr * logf(pr + 1e-10f);
  }
  float E = breduce_sum(lt, red);
  if (tid == 0)
    out[(size_t)B_*O_*T_ + b*T_ + t] = -E / logf((float)O_);
}

extern "C" void kernel_launch(void* const* d_in, const int* in_sizes, int n_in,
                              void* d_out, int out_size, void* d_ws, size_t ws_size,
                              hipStream_t stream) {
  (void)in_sizes; (void)n_in; (void)out_size;
  fp x          = (fp)d_in[0];
  fp conv_w     = (fp)d_in[1];
  fp conv_b     = (fp)d_in[2];
  fp patch_ln_g = (fp)d_in[3];
  fp patch_ln_b = (fp)d_in[4];
  fp pos        = (fp)d_in[5];
  fp kv_w       = (fp)d_in[6];
  fp kv_b       = (fp)d_in[7];
  fp kv_ln_g    = (fp)d_in[8];
  fp kv_ln_b    = (fp)d_in[9];
  fp q_w        = (fp)d_in[10];
  fp q_b        = (fp)d_in[11];
  fp attn_in_w  = (fp)d_in[12];
  fp attn_in_b  = (fp)d_in[13];
  fp attn_out_w = (fp)d_in[14];
  fp attn_out_b = (fp)d_in[15];
  fp syn_w      = (fp)d_in[16];
  fp syn_b      = (fp)d_in[17];
  fp syn_ln_g   = (fp)d_in[18];
  fp syn_ln_b   = (fp)d_in[19];
  fp fc1_w      = (fp)d_in[20];
  fp fc1_b      = (fp)d_in[21];
  fp fc2_w      = (fp)d_in[22];
  fp fc2_b      = (fp)d_in[23];
  fp nlm_T      = (fp)d_in[24];
  fp start_state= (fp)d_in[25];
  fp start_trace= (fp)d_in[26];
  fp decay_a    = (fp)d_in[27];
  fp decay_o    = (fp)d_in[28];
  fp out_w      = (fp)d_in[29];
  fp out_b      = (fp)d_in[30];
  const int* act_left  = (const int*)d_in[31];
  const int* act_right = (const int*)d_in[32];
  const int* out_left  = (const int*)d_in[33];
  const int* out_right = (const int*)d_in[34];

  float* ws = (float*)d_ws;
  float* pt     = ws;                          // precompute only
  float* act    = ws + 0;                      // 32768
  float* trace  = ws + 32768;                  // 819200 -> 851968
  float* aaA    = ws + 851968;                 // 8192
  float* aaB    = ws + 860160;                 // 8192
  float* baA    = ws + 868352;                 // 8192
  float* baB    = ws + 876544;                 // 8192 -> 884736
  float* aoA    = ws + 884736;                 // 16384
  float* aoB    = ws + 901120;                 // 16384
  float* boA    = ws + 917504;                 // 16384
  float* boB    = ws + 933888;                 // 16384 -> 950272
  float* attn_o = ws + 958464;                 // 8192 (fallback only)
  float* ysyn   = ws + 966656;                 // 32768 -> 999424
  float* psum   = ws + 999424;                 // 2048
  float* psq    = ws + 1001472;                // 2048 -> 1003520
  float* av_ws  = ws + 1064960;                // 8192
  float* r_a    = ws + 1073152;                // 512
  float* r_o    = ws + 1073664;                // 1024 -> 1074688
  float* W_qc   = ws + 1074688;                // 262144 -> 1336832
  float* bc     = ws + 1336832;                // 512 -> 1337344 < 1605632
  float* kvb    = ws + 1605632;                // 1605632 -> 3211264
  float* W_so   = ws + 3211264;                // 2097152 -> 5308416
  float* syn_b2 = ws + 5308416;                // 4096 -> 5312512
  const bool big = ws_size >= (size_t)5312512 * 4;

  k_patch_tile<<<dim3(49, 8), dim3(256), 0, stream>>>(x, conv_w, conv_b, pt);
  k_pln<<<dim3(196), dim3(256), 0, stream>>>(pt, patch_ln_g, patch_ln_b, pos);
  k_kv_tile<<<dim3(49, 8), dim3(256), 0, stream>>>(pt, kv_w, kv_b, kvb);
  k_kvln<<<dim3(196), dim3(256), 0, stream>>>(kvb, kv_ln_g, kv_ln_b);
  k_wqc<<<dim3(32, 32), dim3(256), 0, stream>>>(attn_in_w, q_w, W_qc);
  k_wqcb<<<dim3(2), dim3(256), 0, stream>>>(attn_in_w, q_b, attn_in_b, bc);
  if (big) {
    k_wso<<<dim3(64, 8), dim3(256), 0, stream>>>(syn_w, attn_out_w, W_so);
    k_wsob<<<dim3(16), dim3(256), 0, stream>>>(syn_w, syn_b, attn_out_b, syn_b2);
  }
  k_init<<<dim3((B_*N_*M_ + 255)/256), dim3(256), 0, stream>>>(start_state, start_trace,
        out_left, out_right, decay_a, decay_o, act, trace, aaA, baA, aoA, boA, r_a, r_o);

  for (int t = 0; t < T_; t++) {
    k_attout<<<dim3(228), dim3(256), 0, stream>>>(
        act, aaA, aaB, baA, baB, aoA, aoB, boA, boB, r_a, r_o,
        W_qc, bc, kvb, attn_in_w, attn_in_b, out_w, out_b,
        act_left, act_right, out_left, out_right, av_ws, (float*)d_out, t);
    if (big) {
      k_syn2<<<dim3(128, 4), dim3(256), 0, stream>>>(av_ws, act, W_so, syn_w, syn_b2,
                                                     ysyn, psum, psq);
    } else {
      k_ao2<<<dim3(16, 2), dim3(256), 0, stream>>>(av_ws, attn_out_w, attn_out_b, attn_o);
      k_syn<<<dim3(128, 4), dim3(256), 0, stream>>>(attn_o, act, syn_w, syn_b, ysyn, psum, psq);
    }
    k_nlm<<<dim3(N_), dim3(256), 0, stream>>>(trace, ysyn, psum, psq, syn_ln_g, syn_ln_b,
                                              fc1_w, fc1_b, fc2_w, fc2_b, nlm_T, act);
  }
  {
    int t = T_ - 1;
    const float* aoR = (t & 1) ? aoB : aoA;  float* aoW = (t & 1) ? aoA : aoB;
    const float* boR = (t & 1) ? boB : boA;  float* boW = (t & 1) ? boA : boB;
    k_out<<<dim3(50, 2), dim3(256), 0, stream>>>(act, aoR, boR, aoW, boW, r_o,
                                                 out_left, out_right, out_w, out_b,
                                                 (float*)d_out, t);
  }
  k_final<<<dim3(16, 16), dim3(256), 0, stream>>>((float*)d_out);
}